// Round 6
// baseline (83.337 us; speedup 1.0000x reference)
//
#include <hip/hip_runtime.h>
#include <math.h>

#define NKP 133
#define NROWS (256 * NKP)            // 34048 rows of 1024 (x|y halves of 512)
#define NBLOCKS 2048
#define NWAVES (NBLOCKS * 4)         // 8192
#define C2P  14.4269504088896f       // 10*log2(e):  exp(10x) = exp2(C2P*x)
#define NK2  0.02251706f             // log2(e)/(2*5.66^2)
#define RAD  16.98f                  // 5.66*3
#define LN2f 0.69314718055994531f

static __device__ __forceinline__ float fexp2(float x) { return __builtin_amdgcn_exp2f(x); }
static __device__ __forceinline__ float frcp (float x) { return __builtin_amdgcn_rcpf(x); }

__global__ __launch_bounds__(256) void rtmcc_kernel(
    const float* __restrict__ pred,       // [NROWS][1024]
    const float* __restrict__ keypoints,  // [NROWS][3]
    float* __restrict__ partials,         // [NBLOCKS]
    unsigned int* __restrict__ counter,   // [1], zeroed per launch
    float* __restrict__ out)              // [1]
{
    const int wave = threadIdx.x >> 6;
    const int lane = threadIdx.x & 63;
    const int l5   = lane & 31;           // lane within half-group
    const int hgrp = lane >> 5;           // 0 = x half, 1 = y half
    __shared__ float t_em1[256];          // e-1 at d = t-128 (zero for |d|>35)
    __shared__ float t_eg [256];          // e*g
    __shared__ float lds[4];
    __shared__ int   is_last;

    {   // build window tables once per block
        const int t = threadIdx.x;
        const float d = (float)(t - 128);
        float em1 = 0.0f, eg = 0.0f;
        if (fabsf(d) <= 35.0f) {
            const float g = fexp2(-d * d * NK2);   // gaussian target
            const float e = fexp2(g * C2P);        // exp(10*g)
            em1 = e - 1.0f; eg = e * g;
        }
        t_em1[t] = em1; t_eg[t] = eg;
    }
    __syncthreads();

    float acc = 0.0f;
    const int wid = blockIdx.x * 4 + wave;        // 0..8191

    float kx = keypoints[wid * 3 + 0];            // rolling keypoint prefetch
    float ky = keypoints[wid * 3 + 1];
    float kv = keypoints[wid * 3 + 2];

    for (int row = wid; row < NROWS; row += NWAVES) {
        const float kxc = kx, kyc = ky, kvc = kv;
        const int rn = row + NWAVES;
        if (rn < NROWS) {
            kx = keypoints[rn * 3 + 0];
            ky = keypoints[rn * 3 + 1];
            kv = keypoints[rn * 3 + 2];
        }

        const float mux = rintf(kxc * 2.0f);      // half-to-even = jnp.round
        const float muy = rintf(kyc * 2.0f);
        const bool oob = (mux - RAD >= 512.0f) || (muy - RAD >= 512.0f) ||
                         (mux + RAD + 1.0f < 0.0f) || (muy + RAD + 1.0f < 0.0f);
        const bool visible = (kvc >= 0.5f);
        const float w = (visible && oob) ? 0.0f : kvc;
        if (!(w > 0.0f)) continue;                // wave-uniform: zero contribution

        const float mu = hgrp ? muy : mux;
        const float* ph = pred + (size_t)row * 1024 + hgrp * 512;

        // ---- bulk: 16 contiguous floats/lane within this lane's half ----
        const float* p = ph + l5 * 16;
        const float4 q0 = *reinterpret_cast<const float4*>(p);
        const float4 q1 = *reinterpret_cast<const float4*>(p + 4);
        const float4 q2 = *reinterpret_cast<const float4*>(p + 8);
        const float4 q3 = *reinterpret_cast<const float4*>(p + 12);
        const float pv[16] = {q0.x,q0.y,q0.z,q0.w, q1.x,q1.y,q1.z,q1.w,
                              q2.x,q2.y,q2.z,q2.w, q3.x,q3.y,q3.z,q3.w};

        float S = 0.0f, R = 0.0f;   // R accumulates Tp - D = sum(eg) - sum(em1*p) - sum(p)
        #pragma unroll
        for (int u = 0; u < 16; ++u) {
            S += fexp2(C2P * pv[u]);
            R -= pv[u];
        }

        // ---- window: 128 elems around mu, 4/lane, table lookups ----
        float Zw = 0.0f;
        if (visible) {                            // uniform; w>0 implies it here
            const int mui = (int)mu;
            int ws = mui - 64; ws = ws < 0 ? 0 : (ws > 384 ? 384 : ws);
            #pragma unroll
            for (int v = 0; v < 4; ++v) {
                const int idx = ws + l5 + v * 32;    // in [0,511]
                const float pw = ph[idx];            // L1-hot re-read
                int t = idx - mui + 128;             // in [0,255] for mu in [0,512]
                t = t < 0 ? 0 : (t > 255 ? 255 : t); // defensive (zero entries)
                const float em1 = t_em1[t], eg = t_eg[t];
                Zw += em1;
                R  += eg - em1 * pw;
            }
        }

        // ---- 5-step butterfly within each 32-lane half-group ----
        #pragma unroll
        for (int off = 1; off < 32; off <<= 1) {
            S  += __shfl_xor(S,  off, 64);
            Zw += __shfl_xor(Zw, off, 64);
            R  += __shfl_xor(R,  off, 64);
        }

        const float Z = 512.0f + Zw;              // far-field e == 1.0f exactly
        const float loss = 10.0f * R * frcp(Z) + (__log2f(S) - __log2f(Z)) * LN2f;
        acc += w * loss;                          // uniform within each half-group
    }

    // each half-group's loss was accumulated in all 32 of its lanes -> /32 exact
    acc *= (1.0f / (32.0f * 512.0f * 133.0f));
    #pragma unroll
    for (int off = 1; off < 64; off <<= 1) acc += __shfl_xor(acc, off, 64);
    if (lane == 0) lds[wave] = acc;
    __syncthreads();

    if (threadIdx.x == 0) {
        partials[blockIdx.x] = lds[0] + lds[1] + lds[2] + lds[3];
        __threadfence();                          // make partial visible device-wide
        const unsigned int old = atomicAdd(counter, 1u);
        is_last = (old == NBLOCKS - 1) ? 1 : 0;
    }
    __syncthreads();

    if (is_last) {                                // exactly one block; fixed read order
        __threadfence();                          // acquire
        float s = 0.0f;
        for (int i = threadIdx.x; i < NBLOCKS; i += 256)
            s += ((volatile const float*)partials)[i];
        #pragma unroll
        for (int off = 1; off < 64; off <<= 1) s += __shfl_xor(s, off, 64);
        if ((threadIdx.x & 63) == 0) lds[threadIdx.x >> 6] = s;
        __syncthreads();
        if (threadIdx.x == 0) out[0] = lds[0] + lds[1] + lds[2] + lds[3];
    }
}

extern "C" void kernel_launch(void* const* d_in, const int* in_sizes, int n_in,
                              void* d_out, int out_size, void* d_ws, size_t ws_size,
                              hipStream_t stream) {
    const float* pred = (const float*)d_in[0];   // (256,133,1024) fp32
    const float* kpts = (const float*)d_in[1];   // (256,133,3) fp32
    float* out = (float*)d_out;
    float* partials = (float*)d_ws;
    unsigned int* counter = (unsigned int*)((char*)d_ws + NBLOCKS * sizeof(float));

    hipMemsetAsync(counter, 0, sizeof(unsigned int), stream);
    rtmcc_kernel<<<NBLOCKS, 256, 0, stream>>>(pred, kpts, partials, counter, out);
}

// Round 7
// 26.924 us; speedup vs baseline: 3.0953x; 3.0953x over previous
//
#include <hip/hip_runtime.h>
#include <math.h>

#define NKP 133
#define NROWS (256 * NKP)            // 34048 rows of 1024
#define RH_TOTAL (2 * NROWS)         // 68096 row-halves of 512
#define NQUADS (RH_TOTAL / 4)        // 17024 quads (4 row-halves each)
#define NBLOCKS 2048
#define NWAVES (NBLOCKS * 4)         // 8192
#define C2P  14.4269504088896f       // 10*log2(e): exp(10x)=exp2(C2P*x)
#define NK2  0.02251706f             // log2(e)/(2*5.66^2)
#define RAD  16.98f                  // 5.66*3
#define LN2f 0.69314718055994531f

static __device__ __forceinline__ float fexp2(float x) { return __builtin_amdgcn_exp2f(x); }
static __device__ __forceinline__ float frcp (float x) { return __builtin_amdgcn_rcpf(x); }

__global__ __launch_bounds__(256) void rtmcc_partial_kernel(
    const float* __restrict__ pred,       // [RH_TOTAL][512]
    const float* __restrict__ keypoints,  // [NROWS][3]
    float* __restrict__ partials)         // [NBLOCKS]
{
    const int wave = threadIdx.x >> 6;
    const int lane = threadIdx.x & 63;
    const int g    = lane >> 4;           // 16-lane group: one row-half each
    const int l4   = lane & 15;
    const int h    = g & 1;               // group's half: 0=x, 1=y
    __shared__ float t_em1[256];          // e-1 at d=t-128 (zero for |d|>35)
    __shared__ float t_eg [256];          // e*g
    __shared__ float lds[4];

    {   // window tables once per block
        const int t = threadIdx.x;
        const float d = (float)(t - 128);
        float em1 = 0.0f, eg = 0.0f;
        if (fabsf(d) <= 35.0f) {
            const float gg = fexp2(-d * d * NK2);   // gaussian target
            const float e  = fexp2(gg * C2P);       // exp(10*g)
            em1 = e - 1.0f; eg = e * gg;
        }
        t_em1[t] = em1; t_eg[t] = eg;
    }
    __syncthreads();

    float acc = 0.0f;
    const int wid = blockIdx.x * 4 + wave;          // 0..8191

    // rolling keypoint prefetch (per-lane; 2 distinct rows per wave)
    int q = wid;
    {
        const int row = 2 * q + (g >> 1);
        float kx = keypoints[row * 3 + 0];
        float ky = keypoints[row * 3 + 1];
        float kv = keypoints[row * 3 + 2];

        for (; q < NQUADS; q += NWAVES) {
            const float kxc = kx, kyc = ky, kvc = kv;
            const int qn = q + NWAVES;
            if (qn < NQUADS) {
                const int rown = 2 * qn + (g >> 1);
                kx = keypoints[rown * 3 + 0];
                ky = keypoints[rown * 3 + 1];
                kv = keypoints[rown * 3 + 2];
            }

            const float mux = rintf(kxc * 2.0f);    // half-to-even = jnp.round
            const float muy = rintf(kyc * 2.0f);
            const bool oob = (mux - RAD >= 512.0f) || (muy - RAD >= 512.0f) ||
                             (mux + RAD + 1.0f < 0.0f) || (muy + RAD + 1.0f < 0.0f);
            const bool visible = (kvc >= 0.5f);
            const float w = (visible && oob) ? 0.0f : kvc;
            const bool active = (w > 0.0f);         // uniform within 16-lane group

            float S = 0.0f, Zw = 0.0f, R = 0.0f;
            if (active) {
                // group's row-half base (element units)
                const float* ph = pred + (size_t)(4 * q + g) * 512;

                // ---- bulk: 8 float4 loads, column-interleaved so each load
                //      instruction is 4x contiguous 1KB segments (coalesced) ----
                float4 qv[8];
                #pragma unroll
                for (int v = 0; v < 8; ++v)
                    qv[v] = *reinterpret_cast<const float4*>(ph + v * 64 + l4 * 4);

                #pragma unroll
                for (int v = 0; v < 8; ++v) {
                    S += fexp2(C2P * qv[v].x) + fexp2(C2P * qv[v].y)
                       + fexp2(C2P * qv[v].z) + fexp2(C2P * qv[v].w);
                    R -= qv[v].x + qv[v].y + qv[v].z + qv[v].w;
                }

                // ---- window: 128 elems around mu, 8/lane, table lookups ----
                const float mu = h ? muy : mux;
                const int mui = (int)mu;
                int ws = mui - 64; ws = ws < 0 ? 0 : (ws > 384 ? 384 : ws);
                #pragma unroll
                for (int v = 0; v < 8; ++v) {
                    const int idx = ws + l4 + v * 16;     // [ws, ws+128)
                    const float pw = ph[idx];             // L1-hot re-read
                    int t = idx - mui + 128;
                    t = t < 0 ? 0 : (t > 255 ? 255 : t);  // clamped entries are 0
                    const float em1 = t_em1[t], eg = t_eg[t];
                    Zw += em1;
                    R  += eg - em1 * pw;
                }
            }

            // ---- 4-step butterfly within each 16-lane group ----
            #pragma unroll
            for (int off = 1; off < 16; off <<= 1) {
                S  += __shfl_xor(S,  off, 64);
                Zw += __shfl_xor(Zw, off, 64);
                R  += __shfl_xor(R,  off, 64);
            }

            if (active) {
                const float Z = 512.0f + Zw;        // far-field e == 1.0f exactly
                acc += w * (10.0f * R * frcp(Z) + (__log2f(S) - __log2f(Z)) * LN2f);
            }
        }
    }

    // each group's contribution sits in all 16 of its lanes -> /16 exact
    acc *= (1.0f / (16.0f * 512.0f * 133.0f));
    #pragma unroll
    for (int off = 1; off < 64; off <<= 1) acc += __shfl_xor(acc, off, 64);
    if (lane == 0) lds[wave] = acc;
    __syncthreads();
    if (threadIdx.x == 0)
        partials[blockIdx.x] = lds[0] + lds[1] + lds[2] + lds[3];
}

__global__ __launch_bounds__(256) void rtmcc_reduce_kernel(
    const float* __restrict__ partials, float* __restrict__ out)
{
    __shared__ float lds[4];
    float s = 0.0f;
    for (int i = threadIdx.x; i < NBLOCKS; i += 256) s += partials[i];
    #pragma unroll
    for (int off = 1; off < 64; off <<= 1) s += __shfl_xor(s, off, 64);
    if ((threadIdx.x & 63) == 0) lds[threadIdx.x >> 6] = s;
    __syncthreads();
    if (threadIdx.x == 0) out[0] = lds[0] + lds[1] + lds[2] + lds[3];
}

extern "C" void kernel_launch(void* const* d_in, const int* in_sizes, int n_in,
                              void* d_out, int out_size, void* d_ws, size_t ws_size,
                              hipStream_t stream) {
    const float* pred = (const float*)d_in[0];   // (256,133,1024) fp32
    const float* kpts = (const float*)d_in[1];   // (256,133,3) fp32
    float* out = (float*)d_out;
    float* partials = (float*)d_ws;

    rtmcc_partial_kernel<<<NBLOCKS, 256, 0, stream>>>(pred, kpts, partials);
    rtmcc_reduce_kernel<<<1, 256, 0, stream>>>(partials, out);
}